// Round 1
// baseline (1116.739 us; speedup 1.0000x reference)
//
#include <hip/hip_runtime.h>

namespace {
constexpr int TT   = 48;   // T
constexpr int HID  = 64;
constexpr int MH   = 32;   // MEM_HID
constexpr int MS   = 20;   // MEM_SIZE
constexpr int HSTR = 68;   // s_h row stride (floats): 16B-aligned float4 rows, bank-conflict-free
constexpr int QSTR = 34;   // s_q/k/v/memories row stride: 8B-aligned float2, conflict-free
constexpr int SSTR = 50;   // s_score row stride
constexpr float EPS = 1e-8f;
}

__global__ __launch_bounds__(256, 2)
void testam_fused(const float* __restrict__ input,
                  const float* __restrict__ h0,
                  const float* __restrict__ h1,
                  const float* __restrict__ h2,
                  const float* __restrict__ memory,
                  const float* __restrict__ input_query,
                  const float* __restrict__ hid_query,
                  const float* __restrict__ key_w,
                  const float* __restrict__ value_w,
                  float* __restrict__ out)
{
    __shared__ __align__(16) float s_mem[MS * MH];       // 640
    __shared__ __align__(16) float s_iq[2 * MH];         // 64
    __shared__ __align__(16) float s_in[TT * 2];         // 96
    __shared__ __align__(16) float s_memories[TT * QSTR];// 1632
    __shared__ __align__(16) float s_memnorm[TT];        // 48
    __shared__ __align__(16) float s_h[TT * HSTR];       // 3264
    __shared__ __align__(16) float s_wq[HID * MH];       // 2048
    __shared__ __align__(16) float s_wk[HID * MH];       // 2048
    __shared__ __align__(16) float s_wv[HID * MH];       // 2048
    __shared__ __align__(16) float s_q[TT * QSTR];       // 1632
    __shared__ __align__(16) float s_k[TT * QSTR];       // 1632
    __shared__ __align__(16) float s_v[TT * QSTR];       // 1632
    __shared__ __align__(16) float s_score[TT * SSTR];   // 2400
    // total ~76.7 KB -> 2 workgroups / CU

    const int tid = threadIdx.x;
    const size_t bn = blockIdx.x;

    // ---- stage small shared tensors ----
    for (int i = tid; i < MS * MH; i += 256) s_mem[i] = memory[i];
    if (tid < 2 * MH) s_iq[tid] = input_query[tid];
    if (tid < TT * 2) s_in[tid] = input[bn * (TT * 2) + tid];
    __syncthreads();

    // ---- phase A: memory read-out ("memories") ----
    // q_in[t][m] -> s_q (reuse q buffer)
    for (int idx = tid; idx < TT * MH; idx += 256) {
        const int t = idx >> 5, m = idx & 31;
        s_q[t * QSTR + m] = fmaf(s_in[2 * t], s_iq[m], s_in[2 * t + 1] * s_iq[MH + m]);
    }
    __syncthreads();
    // mem energy [48][20] -> s_score
    for (int idx = tid; idx < TT * MS; idx += 256) {
        const int t = idx / MS, s = idx - t * MS;
        float acc = 0.f;
        #pragma unroll
        for (int m = 0; m < MH; ++m)
            acc = fmaf(s_q[t * QSTR + m], s_mem[s * MH + m], acc);
        s_score[t * SSTR + s] = acc;
    }
    __syncthreads();
    // softmax over 20 (one thread per row; cheap)
    if (tid < TT) {
        float mx = -1e30f;
        #pragma unroll
        for (int s = 0; s < MS; ++s) mx = fmaxf(mx, s_score[tid * SSTR + s]);
        float sum = 0.f;
        #pragma unroll
        for (int s = 0; s < MS; ++s) {
            const float ex = __expf(s_score[tid * SSTR + s] - mx);
            s_score[tid * SSTR + s] = ex;
            sum += ex;
        }
        const float inv = 1.f / sum;
        #pragma unroll
        for (int s = 0; s < MS; ++s) s_score[tid * SSTR + s] *= inv;
    }
    __syncthreads();
    // memories[t][m] = score @ memory
    for (int idx = tid; idx < TT * MH; idx += 256) {
        const int t = idx >> 5, m = idx & 31;
        float acc = 0.f;
        #pragma unroll
        for (int s = 0; s < MS; ++s)
            acc = fmaf(s_score[t * SSTR + s], s_mem[s * MH + m], acc);
        s_memories[t * QSTR + m] = acc;
    }
    __syncthreads();
    if (tid < TT) {
        float acc = 0.f;
        #pragma unroll
        for (int m = 0; m < MH; ++m) {
            const float x = s_memories[tid * QSTR + m];
            acc = fmaf(x, x, acc);
        }
        s_memnorm[tid] = sqrtf(acc);
    }
    // (visibility of s_memnorm guaranteed by the sync inside the expert loop)

    const int rg = tid >> 4;   // 0..15
    const int cg = tid & 15;   // 0..15

    for (int e = 0; e < 3; ++e) {
        const float* __restrict__ hp = (e == 0) ? h0 : ((e == 1) ? h1 : h2);

        // ---- stage h_e [48][64] (padded) and the 3 weight matrices ----
        {
            const float4* hsrc4 = reinterpret_cast<const float4*>(hp + bn * (size_t)(TT * HID));
            #pragma unroll
            for (int k = 0; k < 3; ++k) {
                const int j = tid + k * 256;          // j in [0, 768)
                const float4 val = hsrc4[j];
                const int r = j >> 4;                 // 16 float4 per 64-wide row
                const int c = (j & 15) << 2;
                *reinterpret_cast<float4*>(&s_h[r * HSTR + c]) = val;
            }
            const float4* wq4 = reinterpret_cast<const float4*>(hid_query + e * (HID * MH));
            const float4* wk4 = reinterpret_cast<const float4*>(key_w    + e * (HID * MH));
            const float4* wv4 = reinterpret_cast<const float4*>(value_w  + e * (HID * MH));
            float4* dq = reinterpret_cast<float4*>(s_wq);
            float4* dk = reinterpret_cast<float4*>(s_wk);
            float4* dv = reinterpret_cast<float4*>(s_wv);
            #pragma unroll
            for (int k = 0; k < 2; ++k) {
                const int j = tid + k * 256;          // j in [0, 512)
                dq[j] = wq4[j];
                dk[j] = wk4[j];
                dv[j] = wv4[j];
            }
        }
        __syncthreads();

        // ---- q/k/v projection: thread tile = 3 rows x 2 cols x 3 matrices ----
        {
            const int r0 = rg * 3, c0 = cg * 2;
            float aq[3][2] = {{0.f,0.f},{0.f,0.f},{0.f,0.f}};
            float ak[3][2] = {{0.f,0.f},{0.f,0.f},{0.f,0.f}};
            float av[3][2] = {{0.f,0.f},{0.f,0.f},{0.f,0.f}};
            const float* hr0 = &s_h[(r0 + 0) * HSTR];
            const float* hr1 = &s_h[(r0 + 1) * HSTR];
            const float* hr2 = &s_h[(r0 + 2) * HSTR];
            #pragma unroll 8
            for (int h = 0; h < HID; ++h) {
                const float x0 = hr0[h];
                const float x1 = hr1[h];
                const float x2 = hr2[h];
                const float2 wq = *reinterpret_cast<const float2*>(&s_wq[h * MH + c0]);
                const float2 wk = *reinterpret_cast<const float2*>(&s_wk[h * MH + c0]);
                const float2 wv = *reinterpret_cast<const float2*>(&s_wv[h * MH + c0]);
                aq[0][0] = fmaf(x0, wq.x, aq[0][0]); aq[0][1] = fmaf(x0, wq.y, aq[0][1]);
                aq[1][0] = fmaf(x1, wq.x, aq[1][0]); aq[1][1] = fmaf(x1, wq.y, aq[1][1]);
                aq[2][0] = fmaf(x2, wq.x, aq[2][0]); aq[2][1] = fmaf(x2, wq.y, aq[2][1]);
                ak[0][0] = fmaf(x0, wk.x, ak[0][0]); ak[0][1] = fmaf(x0, wk.y, ak[0][1]);
                ak[1][0] = fmaf(x1, wk.x, ak[1][0]); ak[1][1] = fmaf(x1, wk.y, ak[1][1]);
                ak[2][0] = fmaf(x2, wk.x, ak[2][0]); ak[2][1] = fmaf(x2, wk.y, ak[2][1]);
                av[0][0] = fmaf(x0, wv.x, av[0][0]); av[0][1] = fmaf(x0, wv.y, av[0][1]);
                av[1][0] = fmaf(x1, wv.x, av[1][0]); av[1][1] = fmaf(x1, wv.y, av[1][1]);
                av[2][0] = fmaf(x2, wv.x, av[2][0]); av[2][1] = fmaf(x2, wv.y, av[2][1]);
            }
            #pragma unroll
            for (int i = 0; i < 3; ++i) {
                *reinterpret_cast<float2*>(&s_q[(r0 + i) * QSTR + c0]) = make_float2(aq[i][0], aq[i][1]);
                *reinterpret_cast<float2*>(&s_k[(r0 + i) * QSTR + c0]) = make_float2(ak[i][0], ak[i][1]);
                *reinterpret_cast<float2*>(&s_v[(r0 + i) * QSTR + c0]) = make_float2(av[i][0], av[i][1]);
            }
        }
        __syncthreads();

        // ---- energy [48][48]: thread tile 3x3, K = 32 (float2-stepped) ----
        {
            const int t0 = rg * 3, s0 = cg * 3;
            float acc[3][3] = {{0.f,0.f,0.f},{0.f,0.f,0.f},{0.f,0.f,0.f}};
            #pragma unroll 8
            for (int m = 0; m < MH; m += 2) {
                const float2 q0 = *reinterpret_cast<const float2*>(&s_q[(t0 + 0) * QSTR + m]);
                const float2 q1 = *reinterpret_cast<const float2*>(&s_q[(t0 + 1) * QSTR + m]);
                const float2 q2 = *reinterpret_cast<const float2*>(&s_q[(t0 + 2) * QSTR + m]);
                const float2 k0 = *reinterpret_cast<const float2*>(&s_k[(s0 + 0) * QSTR + m]);
                const float2 k1 = *reinterpret_cast<const float2*>(&s_k[(s0 + 1) * QSTR + m]);
                const float2 k2 = *reinterpret_cast<const float2*>(&s_k[(s0 + 2) * QSTR + m]);
                acc[0][0] = fmaf(q0.x, k0.x, fmaf(q0.y, k0.y, acc[0][0]));
                acc[0][1] = fmaf(q0.x, k1.x, fmaf(q0.y, k1.y, acc[0][1]));
                acc[0][2] = fmaf(q0.x, k2.x, fmaf(q0.y, k2.y, acc[0][2]));
                acc[1][0] = fmaf(q1.x, k0.x, fmaf(q1.y, k0.y, acc[1][0]));
                acc[1][1] = fmaf(q1.x, k1.x, fmaf(q1.y, k1.y, acc[1][1]));
                acc[1][2] = fmaf(q1.x, k2.x, fmaf(q1.y, k2.y, acc[1][2]));
                acc[2][0] = fmaf(q2.x, k0.x, fmaf(q2.y, k0.y, acc[2][0]));
                acc[2][1] = fmaf(q2.x, k1.x, fmaf(q2.y, k1.y, acc[2][1]));
                acc[2][2] = fmaf(q2.x, k2.x, fmaf(q2.y, k2.y, acc[2][2]));
            }
            #pragma unroll
            for (int i = 0; i < 3; ++i)
                #pragma unroll
                for (int j = 0; j < 3; ++j)
                    s_score[(t0 + i) * SSTR + (s0 + j)] = acc[i][j];
        }
        __syncthreads();

        // ---- softmax over 48, 4 lanes per row ----
        if (tid < 192) {
            const int t = tid >> 2, l = tid & 3;
            float mx = -1e30f;
            #pragma unroll
            for (int s = 0; s < TT / 4; ++s) mx = fmaxf(mx, s_score[t * SSTR + 4 * s + l]);
            mx = fmaxf(mx, __shfl_xor(mx, 1));
            mx = fmaxf(mx, __shfl_xor(mx, 2));
            float sum = 0.f;
            #pragma unroll
            for (int s = 0; s < TT / 4; ++s) {
                const float ex = __expf(s_score[t * SSTR + 4 * s + l] - mx);
                s_score[t * SSTR + 4 * s + l] = ex;
                sum += ex;
            }
            sum += __shfl_xor(sum, 1);
            sum += __shfl_xor(sum, 2);
            const float inv = 1.f / sum;
            #pragma unroll
            for (int s = 0; s < TT / 4; ++s) s_score[t * SSTR + 4 * s + l] *= inv;
        }
        __syncthreads();

        // ---- att = score @ v (thread tile 3 rows x 2 cols) + cosine vs memories ----
        {
            const int t0 = rg * 3, m0 = cg * 2;
            float a0x = 0.f, a0y = 0.f, a1x = 0.f, a1y = 0.f, a2x = 0.f, a2y = 0.f;
            #pragma unroll 6
            for (int s = 0; s < TT; ++s) {
                const float sc0 = s_score[(t0 + 0) * SSTR + s];
                const float sc1 = s_score[(t0 + 1) * SSTR + s];
                const float sc2 = s_score[(t0 + 2) * SSTR + s];
                const float2 vv = *reinterpret_cast<const float2*>(&s_v[s * QSTR + m0]);
                a0x = fmaf(sc0, vv.x, a0x); a0y = fmaf(sc0, vv.y, a0y);
                a1x = fmaf(sc1, vv.x, a1x); a1y = fmaf(sc1, vv.y, a1y);
                a2x = fmaf(sc2, vv.x, a2x); a2y = fmaf(sc2, vv.y, a2y);
            }
            float num[3], nrm[3];
            {
                const float2 mm0 = *reinterpret_cast<const float2*>(&s_memories[(t0 + 0) * QSTR + m0]);
                const float2 mm1 = *reinterpret_cast<const float2*>(&s_memories[(t0 + 1) * QSTR + m0]);
                const float2 mm2 = *reinterpret_cast<const float2*>(&s_memories[(t0 + 2) * QSTR + m0]);
                num[0] = a0x * mm0.x + a0y * mm0.y;  nrm[0] = a0x * a0x + a0y * a0y;
                num[1] = a1x * mm1.x + a1y * mm1.y;  nrm[1] = a1x * a1x + a1y * a1y;
                num[2] = a2x * mm2.x + a2y * mm2.y;  nrm[2] = a2x * a2x + a2y * a2y;
            }
            #pragma unroll
            for (int i = 0; i < 3; ++i) {
                float nu = num[i], nr = nrm[i];
                nu += __shfl_xor(nu, 1);  nr += __shfl_xor(nr, 1);
                nu += __shfl_xor(nu, 2);  nr += __shfl_xor(nr, 2);
                nu += __shfl_xor(nu, 4);  nr += __shfl_xor(nr, 4);
                nu += __shfl_xor(nu, 8);  nr += __shfl_xor(nr, 8);
                if (cg == 0) {
                    const float den = fmaxf(s_memnorm[t0 + i] * sqrtf(nr), EPS);
                    out[(bn * TT + (t0 + i)) * 3 + e] = nu / den;
                }
            }
        }
        __syncthreads();   // protect s_h/s_w*/s_q/k/v/s_score before next expert
    }
}

extern "C" void kernel_launch(void* const* d_in, const int* in_sizes, int n_in,
                              void* d_out, int out_size, void* d_ws, size_t ws_size,
                              hipStream_t stream) {
    const float* input       = (const float*)d_in[0];
    const float* h0          = (const float*)d_in[1];
    const float* h1          = (const float*)d_in[2];
    const float* h2          = (const float*)d_in[3];
    const float* memory      = (const float*)d_in[4];
    const float* input_query = (const float*)d_in[5];
    const float* hid_query   = (const float*)d_in[6];
    const float* key_w       = (const float*)d_in[7];
    const float* value_w     = (const float*)d_in[8];
    float* out = (float*)d_out;

    const int n_bn = 16 * 1024;   // B * N
    dim3 grid(n_bn), block(256);
    hipLaunchKernelGGL(testam_fused, grid, block, 0, stream,
                       input, h0, h1, h2, memory, input_query,
                       hid_query, key_w, value_w, out);
}

// Round 3
// 505.931 us; speedup vs baseline: 2.2073x; 2.2073x over previous
//
#include <hip/hip_runtime.h>

typedef _Float16 half8 __attribute__((ext_vector_type(8)));
typedef float floatx4 __attribute__((ext_vector_type(4)));

namespace {
constexpr int TT = 48, HID = 64, MH = 32, MS = 20;
constexpr int QSTR = 36;   // f32 stride for q/k rows (144 B)
constexpr int PSTR = 72;   // half stride for P rows (144 B) — aliases q exactly (6912 B)
constexpr int VSTR = 72;   // half stride for vT rows (144 B)
constexpr int MEMSTR = 34; // half stride for memories (scalar reads)

constexpr int OFF_MEMO = 0;       // half[48*34] = 3264
constexpr int OFF_MNRM = 3264;    // f32[48]     = 192
constexpr int EB = 3456;          // expert area base (16B aligned)
constexpr int SZ_Q  = TT * QSTR * 4;   // 6912 (q f32; P half aliases this)
constexpr int SZ_K  = TT * QSTR * 4;   // 6912
constexpr int SZ_VT = MH * VSTR * 2;   // 4608
constexpr int PW = SZ_Q + SZ_K + SZ_VT; // 18432 per wave
constexpr int OFF_K = SZ_Q, OFF_VT = SZ_Q + SZ_K;
// phase-A scratch aliases the expert area (dead after the single barrier)
constexpr int OFF_SMEM = EB;          // f32[20*32] = 2560
constexpr int OFF_SIQ  = EB + 2560;   // f32[64]
constexpr int OFF_SIN  = EB + 2816;   // f32[96]
constexpr int OFF_QIN  = EB + 3200;   // f32[48*33] = 6336
constexpr int OFF_EN   = EB + 9536;   // f32[48*21] = 4032
constexpr int LDS_BYTES = EB + 3 * PW; // 58752 -> 2 blocks/CU
}

// Pre-convert the 9 weight matrices [e][64][32] f32 into f16 B-fragment order:
// frag id = ((mat*3+e)*2+kk)*2+nb ; element j of lane l is W[e][kk*32+(l>>4)*8+j][nb*16+(l&15)]
__global__ void prep_wfrag(const float* __restrict__ hid_query,
                           const float* __restrict__ key_w,
                           const float* __restrict__ value_w,
                           _Float16* __restrict__ wfrag)
{
    int idx = blockIdx.x * 256 + threadIdx.x;
    if (idx >= 3 * 3 * 2 * 2 * 64 * 8) return;   // 18432
    int j    = idx & 7;
    int lane = (idx >> 3) & 63;
    int nb   = (idx >> 9) & 1;
    int kk   = (idx >> 10) & 1;
    int rest = idx >> 11;            // mat*3 + e
    int e = rest % 3, mat = rest / 3;
    const float* W = (mat == 0) ? hid_query : (mat == 1 ? key_w : value_w);
    int h = kk * 32 + (lane >> 4) * 8 + j;
    int m = nb * 16 + (lane & 15);
    wfrag[idx] = (_Float16)W[((size_t)e * HID + h) * MH + m];
}

__global__ __launch_bounds__(192, 1)
void testam_mfma(const float* __restrict__ input,
                 const float* __restrict__ h0,
                 const float* __restrict__ h1,
                 const float* __restrict__ h2,
                 const float* __restrict__ memory,
                 const float* __restrict__ input_query,
                 const _Float16* __restrict__ wfrag,
                 float* __restrict__ out)
{
    __shared__ __align__(16) char smem[LDS_BYTES];
    const int tid  = threadIdx.x;
    const int lane = tid & 63;
    const size_t bn = blockIdx.x;

    _Float16* s_memo = (_Float16*)(smem + OFF_MEMO);
    float*    s_mnrm = (float*)(smem + OFF_MNRM);

    // ================= phase A: memory read-out (cooperative, fp32) ==========
    {
        float* s_mem = (float*)(smem + OFF_SMEM);
        float* s_iq  = (float*)(smem + OFF_SIQ);
        float* s_in  = (float*)(smem + OFF_SIN);
        float* s_qin = (float*)(smem + OFF_QIN);
        float* s_en  = (float*)(smem + OFF_EN);

        for (int i = tid; i < MS * MH; i += 192) s_mem[i] = memory[i];
        if (tid < 64) s_iq[tid] = input_query[tid];
        if (tid < 96) s_in[tid] = input[bn * 96 + tid];
        __syncthreads();
        for (int i = tid; i < TT * MH; i += 192) {
            int t = i >> 5, m = i & 31;
            s_qin[t * 33 + m] = fmaf(s_in[2 * t], s_iq[m], s_in[2 * t + 1] * s_iq[32 + m]);
        }
        __syncthreads();
        for (int i = tid; i < TT * MS; i += 192) {
            int t = i / MS, s = i - t * MS;
            float acc = 0.f;
            #pragma unroll
            for (int m = 0; m < MH; ++m) acc = fmaf(s_qin[t * 33 + m], s_mem[s * 32 + m], acc);
            s_en[t * 21 + s] = acc;
        }
        __syncthreads();
        {   // exp(E - rowmax); the softmax denominator cancels in the cosine
            int t = tid >> 2, l = tid & 3;
            float mx = -1e30f;
            #pragma unroll
            for (int i = 0; i < 5; ++i) mx = fmaxf(mx, s_en[t * 21 + 4 * i + l]);
            mx = fmaxf(mx, __shfl_xor(mx, 1));
            mx = fmaxf(mx, __shfl_xor(mx, 2));
            #pragma unroll
            for (int i = 0; i < 5; ++i) {
                int idx = t * 21 + 4 * i + l;
                s_en[idx] = __expf(s_en[idx] - mx);
            }
        }
        __syncthreads();
        for (int i = tid; i < TT * MH; i += 192) {
            int t = i >> 5, m = i & 31;
            float acc = 0.f;
            #pragma unroll
            for (int s = 0; s < MS; ++s) acc = fmaf(s_en[t * 21 + s], s_mem[s * 32 + m], acc);
            s_memo[t * MEMSTR + m] = (_Float16)acc;   // unnormalized; scale cancels
        }
        __syncthreads();
        if (tid < TT) {
            float acc = 0.f;
            #pragma unroll
            for (int m = 0; m < MH; ++m) {
                float x = (float)s_memo[tid * MEMSTR + m];
                acc = fmaf(x, x, acc);
            }
            s_mnrm[tid] = sqrtf(acc);
        }
        __syncthreads();   // ONLY barrier boundary: experts are wave-private after this
    }

    // ================= per-expert: one wave per expert, no barriers ==========
    const int e = tid >> 6;
    const int r = lane & 15, g = lane >> 4;
    char* wb = smem + EB + e * PW;
    float*    s_q  = (float*)wb;
    float*    s_k  = (float*)(wb + OFF_K);
    _Float16* s_p  = (_Float16*)wb;            // aliases s_q (q dead by then)
    _Float16* s_vt = (_Float16*)(wb + OFF_VT);

    const float* hp = (e == 0) ? h0 : (e == 1 ? h1 : h2);
    const float* hb = hp + bn * (size_t)(TT * HID);

    // ---- A-fragments of h, split hi/lo f16 (3xTF32-style) ----
    half8 Ahi[3][2], Alo[3][2];
    #pragma unroll
    for (int tb = 0; tb < 3; ++tb)
        #pragma unroll
        for (int kk = 0; kk < 2; ++kk) {
            const float* src = hb + (tb * 16 + r) * HID + kk * 32 + g * 8;
            float4 x0 = *(const float4*)src;
            float4 x1 = *(const float4*)(src + 4);
            float xs[8] = {x0.x, x0.y, x0.z, x0.w, x1.x, x1.y, x1.z, x1.w};
            half8 hi, lo;
            #pragma unroll
            for (int j = 0; j < 8; ++j) {
                _Float16 hh = (_Float16)xs[j];
                hi[j] = hh;
                lo[j] = (_Float16)(xs[j] - (float)hh);
            }
            Ahi[tb][kk] = hi; Alo[tb][kk] = lo;
        }

    // ---- B-fragments of wq/wk/wv from precomputed f16 (L2-resident) ----
    half8 WB[3][2][2];
    #pragma unroll
    for (int mat = 0; mat < 3; ++mat)
        #pragma unroll
        for (int kk = 0; kk < 2; ++kk)
            #pragma unroll
            for (int nb = 0; nb < 2; ++nb) {
                int fid = ((mat * 3 + e) * 2 + kk) * 2 + nb;
                WB[mat][kk][nb] = *(const half8*)(wfrag + (size_t)(fid * 64 + lane) * 8);
            }

    // ---- projections: acc = (h_hi + h_lo) @ w ----
    #pragma unroll
    for (int mat = 0; mat < 3; ++mat) {
        floatx4 acc[3][2];
        #pragma unroll
        for (int tb = 0; tb < 3; ++tb)
            #pragma unroll
            for (int nb = 0; nb < 2; ++nb) acc[tb][nb] = (floatx4)0.f;
        #pragma unroll
        for (int kk = 0; kk < 2; ++kk)
            #pragma unroll
            for (int tb = 0; tb < 3; ++tb)
                #pragma unroll
                for (int nb = 0; nb < 2; ++nb) {
                    acc[tb][nb] = __builtin_amdgcn_mfma_f32_16x16x32_f16(Alo[tb][kk], WB[mat][kk][nb], acc[tb][nb], 0, 0, 0);
                    acc[tb][nb] = __builtin_amdgcn_mfma_f32_16x16x32_f16(Ahi[tb][kk], WB[mat][kk][nb], acc[tb][nb], 0, 0, 0);
                }
        if (mat < 2) {          // q, k kept in f32 for the split-precision energy
            float* dst = (mat == 0) ? s_q : s_k;
            #pragma unroll
            for (int tb = 0; tb < 3; ++tb)
                #pragma unroll
                for (int nb = 0; nb < 2; ++nb)
                    #pragma unroll
                    for (int rr = 0; rr < 4; ++rr)
                        dst[(tb * 16 + g * 4 + rr) * QSTR + nb * 16 + r] = acc[tb][nb][rr];
        } else {                // v -> transposed f16 (B-operand of PV)
            #pragma unroll
            for (int tb = 0; tb < 3; ++tb)
                #pragma unroll
                for (int nb = 0; nb < 2; ++nb)
                    #pragma unroll
                    for (int rr = 0; rr < 4; ++rr)
                        s_vt[(nb * 16 + r) * VSTR + tb * 16 + g * 4 + rr] = (_Float16)acc[tb][nb][rr];
        }
    }
    // zero v^T K-pad cols 48..63 (PV reads them; 0*Inf=NaN if left as garbage)
    for (int i = lane; i < 32 * 8; i += 64) {       // 256 dwords
        int row = i >> 3, c = 48 + ((i & 7) << 1);
        *(uint32_t*)&s_vt[row * VSTR + c] = 0u;
    }
    // order the type-punned LDS stores above before the float4 loads below
    asm volatile("" ::: "memory");

    // ---- energy = q k^T with hi/lo split (drop lo*lo) ----
    half8 qhi[3], qlo[3], khi[3], klo[3];
    #pragma unroll
    for (int tb = 0; tb < 3; ++tb) {
        const float* qs = &s_q[(tb * 16 + r) * QSTR + g * 8];
        const float* ks = &s_k[(tb * 16 + r) * QSTR + g * 8];
        float4 q0 = *(const float4*)qs, q1 = *(const float4*)(qs + 4);
        float4 k0 = *(const float4*)ks, k1 = *(const float4*)(ks + 4);
        float qf[8] = {q0.x,q0.y,q0.z,q0.w,q1.x,q1.y,q1.z,q1.w};
        float kf[8] = {k0.x,k0.y,k0.z,k0.w,k1.x,k1.y,k1.z,k1.w};
        half8 a, b, c, d;
        #pragma unroll
        for (int j = 0; j < 8; ++j) {
            _Float16 hq = (_Float16)qf[j]; a[j] = hq; b[j] = (_Float16)(qf[j] - (float)hq);
            _Float16 hk = (_Float16)kf[j]; c[j] = hk; d[j] = (_Float16)(kf[j] - (float)hk);
        }
        qhi[tb] = a; qlo[tb] = b; khi[tb] = c; klo[tb] = d;
    }
    floatx4 E[3][3];
    #pragma unroll
    for (int tb = 0; tb < 3; ++tb)
        #pragma unroll
        for (int sb = 0; sb < 3; ++sb) {
            floatx4 a = (floatx4)0.f;
            a = __builtin_amdgcn_mfma_f32_16x16x32_f16(qlo[tb], khi[sb], a, 0, 0, 0);
            a = __builtin_amdgcn_mfma_f32_16x16x32_f16(qhi[tb], klo[sb], a, 0, 0, 0);
            a = __builtin_amdgcn_mfma_f32_16x16x32_f16(qhi[tb], khi[sb], a, 0, 0, 0);
            E[tb][sb] = a;
        }
    // q/k loads (float) complete before the half/uint stores into the alias below
    asm volatile("" ::: "memory");

    // ---- softmax numerators only (denominator cancels in cosine) ----
    float P[3][3][4];
    #pragma unroll
    for (int tb = 0; tb < 3; ++tb)
        #pragma unroll
        for (int rr = 0; rr < 4; ++rr) {
            float mx = fmaxf(fmaxf(E[tb][0][rr], E[tb][1][rr]), E[tb][2][rr]);
            mx = fmaxf(mx, __shfl_xor(mx, 1));
            mx = fmaxf(mx, __shfl_xor(mx, 2));
            mx = fmaxf(mx, __shfl_xor(mx, 4));
            mx = fmaxf(mx, __shfl_xor(mx, 8));
            #pragma unroll
            for (int sb = 0; sb < 3; ++sb)
                P[tb][sb][rr] = __expf(E[tb][sb][rr] - mx);
        }

    // ---- write P (f16) into the q alias; zero K-pad cols 48..63 ----
    for (int i = lane; i < TT * 8; i += 64) {         // 384 dwords of zero pad
        int row = i >> 3, c = 48 + ((i & 7) << 1);
        *(uint32_t*)&s_p[row * PSTR + c] = 0u;
    }
    #pragma unroll
    for (int tb = 0; tb < 3; ++tb)
        #pragma unroll
        for (int sb = 0; sb < 3; ++sb)
            #pragma unroll
            for (int rr = 0; rr < 4; ++rr)
                s_p[(tb * 16 + g * 4 + rr) * PSTR + sb * 16 + r] = (_Float16)P[tb][sb][rr];
    // order P/pad stores before the half8 PV loads
    asm volatile("" ::: "memory");

    // ---- att = P @ v  (K padded 48->64, both operands' pad zeroed) ----
    floatx4 att[3][2];
    #pragma unroll
    for (int tb = 0; tb < 3; ++tb) { att[tb][0] = (floatx4)0.f; att[tb][1] = (floatx4)0.f; }
    #pragma unroll
    for (int kk = 0; kk < 2; ++kk) {
        half8 vb0 = *(const half8*)&s_vt[(0 * 16 + r) * VSTR + kk * 32 + g * 8];
        half8 vb1 = *(const half8*)&s_vt[(1 * 16 + r) * VSTR + kk * 32 + g * 8];
        #pragma unroll
        for (int tb = 0; tb < 3; ++tb) {
            half8 pa = *(const half8*)&s_p[(tb * 16 + r) * PSTR + kk * 32 + g * 8];
            att[tb][0] = __builtin_amdgcn_mfma_f32_16x16x32_f16(pa, vb0, att[tb][0], 0, 0, 0);
            att[tb][1] = __builtin_amdgcn_mfma_f32_16x16x32_f16(pa, vb1, att[tb][1], 0, 0, 0);
        }
    }

    // ---- cosine vs memories; 16-lane xor reduce over the 32 m-columns ----
    #pragma unroll
    for (int tb = 0; tb < 3; ++tb)
        #pragma unroll
        for (int rr = 0; rr < 4; ++rr) {
            int t = tb * 16 + g * 4 + rr;
            float a0 = att[tb][0][rr], a1 = att[tb][1][rr];
            float m0 = (float)s_memo[t * MEMSTR + r];
            float m1 = (float)s_memo[t * MEMSTR + 16 + r];
            float nu = a0 * m0 + a1 * m1;
            float nr = a0 * a0 + a1 * a1;
            nu += __shfl_xor(nu, 1); nr += __shfl_xor(nr, 1);
            nu += __shfl_xor(nu, 2); nr += __shfl_xor(nr, 2);
            nu += __shfl_xor(nu, 4); nr += __shfl_xor(nr, 4);
            nu += __shfl_xor(nu, 8); nr += __shfl_xor(nr, 8);
            if (r == 0) {
                float den = fmaxf(s_mnrm[t] * sqrtf(nr), 1e-8f);
                out[(bn * TT + t) * 3 + e] = nu / den;
            }
        }
}

extern "C" void kernel_launch(void* const* d_in, const int* in_sizes, int n_in,
                              void* d_out, int out_size, void* d_ws, size_t ws_size,
                              hipStream_t stream) {
    const float* input       = (const float*)d_in[0];
    const float* h0          = (const float*)d_in[1];
    const float* h1          = (const float*)d_in[2];
    const float* h2          = (const float*)d_in[3];
    const float* memory      = (const float*)d_in[4];
    const float* input_query = (const float*)d_in[5];
    const float* hid_query   = (const float*)d_in[6];
    const float* key_w       = (const float*)d_in[7];
    const float* value_w     = (const float*)d_in[8];
    float* out = (float*)d_out;
    _Float16* wfrag = (_Float16*)d_ws;   // 36864 bytes used

    hipLaunchKernelGGL(prep_wfrag, dim3(72), dim3(256), 0, stream,
                       hid_query, key_w, value_w, wfrag);
    hipLaunchKernelGGL(testam_mfma, dim3(16 * 1024), dim3(192), 0, stream,
                       input, h0, h1, h2, memory, input_query, wfrag, out);
}

// Round 4
// 297.668 us; speedup vs baseline: 3.7516x; 1.6996x over previous
//
#include <hip/hip_runtime.h>

typedef _Float16 half8 __attribute__((ext_vector_type(8)));
typedef float floatx4 __attribute__((ext_vector_type(4)));

namespace {
constexpr int TT = 48, HID = 64, MH = 32, MS = 20;
constexpr int QSTR = 36;   // f32 dwords per q/k row (144 B, 16B-aligned, conflict-free b128)
constexpr int PSTR = 72;   // halves per P row (144 B) — P aliases q exactly
constexpr int VSTR = 72;   // halves per vT row (144 B)
constexpr int PMSTR = 40;  // halves per phase-A P row (80 B, 16B-aligned)
constexpr int OFF_K = 6912, OFF_VT = 13824;
constexpr int LDS_BYTES = 18432;          // 8 blocks/CU (147456 of 163840 B)
// d_ws offsets in half elements
constexpr int WS_WFRAG = 0;               // 18432 halves
constexpr int WS_MEMA  = 18432;           // 2*64*8 = 1024 halves (A-frag of mem, rows s, zero s>=20)
constexpr int WS_MEMB  = 19456;           // 1024 halves (B-frag of mem, k=s, col m, zero s>=20)
}

// Pre-convert weights + memory bank into f16 MFMA-fragment order.
__global__ void prep_frags(const float* __restrict__ hid_query,
                           const float* __restrict__ key_w,
                           const float* __restrict__ value_w,
                           const float* __restrict__ memory,
                           _Float16* __restrict__ ws)
{
    int idx = blockIdx.x * 256 + threadIdx.x;
    if (idx < 18432) {   // weight B-frags: ((mat*3+e)*2+kk)*2+nb ; W[kk*32+(l>>4)*8+j][nb*16+(l&15)]
        int j = idx & 7, lane = (idx >> 3) & 63, nb = (idx >> 9) & 1, kk = (idx >> 10) & 1;
        int rest = idx >> 11;            // mat*3 + e
        int e = rest % 3, mat = rest / 3;
        const float* W = (mat == 0) ? hid_query : (mat == 1 ? key_w : value_w);
        int h = kk * 32 + (lane >> 4) * 8 + j;
        int m = nb * 16 + (lane & 15);
        ws[WS_WFRAG + idx] = (_Float16)W[((size_t)e * HID + h) * MH + m];
    } else if (idx < WS_MEMA + 1024) {   // mem A-frag: row s = 16sb + (l&15), k m = (l>>4)*8 + j
        int i = idx - WS_MEMA;
        int j = i & 7, lane = (i >> 3) & 63, sb = i >> 9;
        int s = 16 * sb + (lane & 15);
        int m = (lane >> 4) * 8 + j;
        ws[idx] = (s < MS) ? (_Float16)memory[s * MH + m] : (_Float16)0.f;
    } else if (idx < WS_MEMB + 1024) {   // mem B-frag: k s = (l>>4)*8 + j, col m = 16nb + (l&15)
        int i = idx - WS_MEMB;
        int j = i & 7, lane = (i >> 3) & 63, nb = i >> 9;
        int s = (lane >> 4) * 8 + j;
        int m = 16 * nb + (lane & 15);
        ws[idx] = (s < MS) ? (_Float16)memory[s * MH + m] : (_Float16)0.f;
    }
}

// One wave per (bn, expert). No __syncthreads anywhere.
__global__ __launch_bounds__(64, 2)
void testam_wave(const float* __restrict__ input,
                 const float* __restrict__ h0,
                 const float* __restrict__ h1,
                 const float* __restrict__ h2,
                 const float* __restrict__ input_query,
                 const _Float16* __restrict__ ws,
                 float* __restrict__ out)
{
    __shared__ __align__(16) char smem[LDS_BYTES];
    const int lane = threadIdx.x;
    const int r = lane & 15, g = lane >> 4;
    const size_t bn = blockIdx.x;
    const int e = blockIdx.y;

    float*    s_q  = (float*)smem;              // [48][36] f32
    float*    s_k  = (float*)(smem + OFF_K);    // [48][36] f32
    _Float16* s_vt = (_Float16*)(smem + OFF_VT);// [32][72] half
    _Float16* s_pm = (_Float16*)smem;           // phase-A P [48][40] half (aliases q)
    _Float16* s_p  = (_Float16*)smem;           // PV P [48][72] half (aliases q)

    // ================= phase A: memory read-out, all-MFMA, wave-private =====
    half8 memA0 = *(const half8*)(ws + WS_MEMA + (size_t)lane * 8);
    half8 memA1 = *(const half8*)(ws + WS_MEMA + (size_t)(64 + lane) * 8);
    half8 memB0 = *(const half8*)(ws + WS_MEMB + (size_t)lane * 8);
    half8 memB1 = *(const half8*)(ws + WS_MEMB + (size_t)(64 + lane) * 8);

    float iq0[8], iq1[8];
    #pragma unroll
    for (int j = 0; j < 8; ++j) {
        iq0[j] = input_query[g * 8 + j];
        iq1[j] = input_query[32 + g * 8 + j];
    }

    floatx4 Em[2][3];
    #pragma unroll
    for (int tb = 0; tb < 3; ++tb) {
        const float2 in2 = *(const float2*)(input + bn * 96 + (16 * tb + r) * 2);
        half8 qb;
        #pragma unroll
        for (int j = 0; j < 8; ++j)
            qb[j] = (_Float16)(in2.x * iq0[j] + in2.y * iq1[j]);
        Em[0][tb] = __builtin_amdgcn_mfma_f32_16x16x32_f16(memA0, qb, (floatx4)0.f, 0, 0, 0);
        Em[1][tb] = __builtin_amdgcn_mfma_f32_16x16x32_f16(memA1, qb, (floatx4)0.f, 0, 0, 0);
    }
    // softmax numerators over s (denominator cancels in cosine; s>=20 rows are
    // zero in both mem frags so no masking needed)
    #pragma unroll
    for (int tb = 0; tb < 3; ++tb) {
        float mx = Em[0][tb][0];
        #pragma unroll
        for (int rr = 1; rr < 4; ++rr) mx = fmaxf(mx, Em[0][tb][rr]);
        #pragma unroll
        for (int rr = 0; rr < 4; ++rr) mx = fmaxf(mx, Em[1][tb][rr]);
        mx = fmaxf(mx, __shfl_xor(mx, 16));
        mx = fmaxf(mx, __shfl_xor(mx, 32));
        #pragma unroll
        for (int sb = 0; sb < 2; ++sb)
            #pragma unroll
            for (int rr = 0; rr < 4; ++rr)
                s_pm[(16 * tb + r) * PMSTR + 16 * sb + 4 * g + rr] =
                    (_Float16)__expf(Em[sb][tb][rr] - mx);
    }
    asm volatile("" ::: "memory");
    floatx4 mems[3][2];   // memories[t][m] in C-layout == att layout; stays in regs
    #pragma unroll
    for (int tb = 0; tb < 3; ++tb) {
        half8 pA = *(const half8*)&s_pm[(16 * tb + r) * PMSTR + g * 8];
        mems[tb][0] = __builtin_amdgcn_mfma_f32_16x16x32_f16(pA, memB0, (floatx4)0.f, 0, 0, 0);
        mems[tb][1] = __builtin_amdgcn_mfma_f32_16x16x32_f16(pA, memB1, (floatx4)0.f, 0, 0, 0);
    }
    asm volatile("" ::: "memory");   // s_pm (q alias) dead before proj stores

    // ================= phase B: per-expert attention ========================
    const float* hp = (e == 0) ? h0 : (e == 1 ? h1 : h2);
    const float* hb = hp + bn * (size_t)(TT * HID);

    // A-fragments of h, split hi/lo f16
    half8 Ahi[3][2], Alo[3][2];
    #pragma unroll
    for (int tb = 0; tb < 3; ++tb)
        #pragma unroll
        for (int kk = 0; kk < 2; ++kk) {
            const float* src = hb + (tb * 16 + r) * HID + kk * 32 + g * 8;
            float4 x0 = *(const float4*)src;
            float4 x1 = *(const float4*)(src + 4);
            float xs[8] = {x0.x, x0.y, x0.z, x0.w, x1.x, x1.y, x1.z, x1.w};
            half8 hi, lo;
            #pragma unroll
            for (int j = 0; j < 8; ++j) {
                _Float16 hh = (_Float16)xs[j];
                hi[j] = hh;
                lo[j] = (_Float16)(xs[j] - (float)hh);
            }
            Ahi[tb][kk] = hi; Alo[tb][kk] = lo;
        }

    // projections: acc = (h_hi + h_lo) @ w ; weights loaded per-mat (caps VGPR)
    #pragma unroll
    for (int mat = 0; mat < 3; ++mat) {
        half8 WBf[2][2];
        #pragma unroll
        for (int kk = 0; kk < 2; ++kk)
            #pragma unroll
            for (int nb = 0; nb < 2; ++nb) {
                int fid = ((mat * 3 + e) * 2 + kk) * 2 + nb;
                WBf[kk][nb] = *(const half8*)(ws + WS_WFRAG + (size_t)(fid * 64 + lane) * 8);
            }
        floatx4 acc[3][2];
        #pragma unroll
        for (int tb = 0; tb < 3; ++tb)
            #pragma unroll
            for (int nb = 0; nb < 2; ++nb) acc[tb][nb] = (floatx4)0.f;
        #pragma unroll
        for (int kk = 0; kk < 2; ++kk)
            #pragma unroll
            for (int tb = 0; tb < 3; ++tb)
                #pragma unroll
                for (int nb = 0; nb < 2; ++nb) {
                    acc[tb][nb] = __builtin_amdgcn_mfma_f32_16x16x32_f16(Alo[tb][kk], WBf[kk][nb], acc[tb][nb], 0, 0, 0);
                    acc[tb][nb] = __builtin_amdgcn_mfma_f32_16x16x32_f16(Ahi[tb][kk], WBf[kk][nb], acc[tb][nb], 0, 0, 0);
                }
        if (mat < 2) {          // q, k kept f32 for split-precision energy
            float* dst = (mat == 0) ? s_q : s_k;
            #pragma unroll
            for (int tb = 0; tb < 3; ++tb)
                #pragma unroll
                for (int nb = 0; nb < 2; ++nb)
                    #pragma unroll
                    for (int rr = 0; rr < 4; ++rr)
                        dst[(tb * 16 + g * 4 + rr) * QSTR + nb * 16 + r] = acc[tb][nb][rr];
        } else {                // v -> transposed f16 (B-operand of PV)
            #pragma unroll
            for (int tb = 0; tb < 3; ++tb)
                #pragma unroll
                for (int nb = 0; nb < 2; ++nb)
                    #pragma unroll
                    for (int rr = 0; rr < 4; ++rr)
                        s_vt[(nb * 16 + r) * VSTR + tb * 16 + g * 4 + rr] = (_Float16)acc[tb][nb][rr];
        }
    }
    // zero v^T K-pad cols 48..63 (avoid 0*garbage=NaN in PV)
    #pragma unroll
    for (int i = lane; i < 32 * 8; i += 64) {
        int row = i >> 3, c = 48 + ((i & 7) << 1);
        *(uint32_t*)&s_vt[row * VSTR + c] = 0u;
    }
    asm volatile("" ::: "memory");

    // energy = q k^T with hi/lo split (drop lo*lo)
    half8 qhi[3], qlo[3], khi[3], klo[3];
    #pragma unroll
    for (int tb = 0; tb < 3; ++tb) {
        const float* qs = &s_q[(tb * 16 + r) * QSTR + g * 8];
        const float* ks = &s_k[(tb * 16 + r) * QSTR + g * 8];
        float4 q0 = *(const float4*)qs, q1 = *(const float4*)(qs + 4);
        float4 k0 = *(const float4*)ks, k1 = *(const float4*)(ks + 4);
        float qf[8] = {q0.x,q0.y,q0.z,q0.w,q1.x,q1.y,q1.z,q1.w};
        float kf[8] = {k0.x,k0.y,k0.z,k0.w,k1.x,k1.y,k1.z,k1.w};
        half8 a, b, c, d;
        #pragma unroll
        for (int j = 0; j < 8; ++j) {
            _Float16 hq = (_Float16)qf[j]; a[j] = hq; b[j] = (_Float16)(qf[j] - (float)hq);
            _Float16 hk = (_Float16)kf[j]; c[j] = hk; d[j] = (_Float16)(kf[j] - (float)hk);
        }
        qhi[tb] = a; qlo[tb] = b; khi[tb] = c; klo[tb] = d;
    }
    floatx4 E[3][3];
    #pragma unroll
    for (int tb = 0; tb < 3; ++tb)
        #pragma unroll
        for (int sb = 0; sb < 3; ++sb) {
            floatx4 a = (floatx4)0.f;
            a = __builtin_amdgcn_mfma_f32_16x16x32_f16(qlo[tb], khi[sb], a, 0, 0, 0);
            a = __builtin_amdgcn_mfma_f32_16x16x32_f16(qhi[tb], klo[sb], a, 0, 0, 0);
            a = __builtin_amdgcn_mfma_f32_16x16x32_f16(qhi[tb], khi[sb], a, 0, 0, 0);
            E[tb][sb] = a;
        }
    asm volatile("" ::: "memory");   // q/k f32 loads done before P (alias) stores

    // softmax numerators only (denominator cancels in cosine)
    float P[3][3][4];
    #pragma unroll
    for (int tb = 0; tb < 3; ++tb)
        #pragma unroll
        for (int rr = 0; rr < 4; ++rr) {
            float mx = fmaxf(fmaxf(E[tb][0][rr], E[tb][1][rr]), E[tb][2][rr]);
            mx = fmaxf(mx, __shfl_xor(mx, 1));
            mx = fmaxf(mx, __shfl_xor(mx, 2));
            mx = fmaxf(mx, __shfl_xor(mx, 4));
            mx = fmaxf(mx, __shfl_xor(mx, 8));
            #pragma unroll
            for (int sb = 0; sb < 3; ++sb)
                P[tb][sb][rr] = __expf(E[tb][sb][rr] - mx);
        }

    // write P (f16) into q alias; zero K-pad cols 48..63
    #pragma unroll
    for (int i = lane; i < TT * 8; i += 64) {
        int row = i >> 3, c = 48 + ((i & 7) << 1);
        *(uint32_t*)&s_p[row * PSTR + c] = 0u;
    }
    #pragma unroll
    for (int tb = 0; tb < 3; ++tb)
        #pragma unroll
        for (int sb = 0; sb < 3; ++sb)
            #pragma unroll
            for (int rr = 0; rr < 4; ++rr)
                s_p[(tb * 16 + g * 4 + rr) * PSTR + sb * 16 + r] = (_Float16)P[tb][sb][rr];
    asm volatile("" ::: "memory");

    // att = P @ v (K padded 48->64, both pads zeroed)
    floatx4 att[3][2];
    #pragma unroll
    for (int tb = 0; tb < 3; ++tb) { att[tb][0] = (floatx4)0.f; att[tb][1] = (floatx4)0.f; }
    #pragma unroll
    for (int kk = 0; kk < 2; ++kk) {
        half8 vb0 = *(const half8*)&s_vt[(0 * 16 + r) * VSTR + kk * 32 + g * 8];
        half8 vb1 = *(const half8*)&s_vt[(1 * 16 + r) * VSTR + kk * 32 + g * 8];
        #pragma unroll
        for (int tb = 0; tb < 3; ++tb) {
            half8 pa = *(const half8*)&s_p[(tb * 16 + r) * PSTR + kk * 32 + g * 8];
            att[tb][0] = __builtin_amdgcn_mfma_f32_16x16x32_f16(pa, vb0, att[tb][0], 0, 0, 0);
            att[tb][1] = __builtin_amdgcn_mfma_f32_16x16x32_f16(pa, vb1, att[tb][1], 0, 0, 0);
        }
    }

    // cosine vs in-register memories; 3-way xor reduce over the 16 r-lanes
    #pragma unroll
    for (int tb = 0; tb < 3; ++tb)
        #pragma unroll
        for (int rr = 0; rr < 4; ++rr) {
            int t = 16 * tb + 4 * g + rr;
            float a0 = att[tb][0][rr], a1 = att[tb][1][rr];
            float m0 = mems[tb][0][rr], m1 = mems[tb][1][rr];
            float nu = a0 * m0 + a1 * m1;
            float nr = a0 * a0 + a1 * a1;
            float nm = m0 * m0 + m1 * m1;
            nu += __shfl_xor(nu, 1); nr += __shfl_xor(nr, 1); nm += __shfl_xor(nm, 1);
            nu += __shfl_xor(nu, 2); nr += __shfl_xor(nr, 2); nm += __shfl_xor(nm, 2);
            nu += __shfl_xor(nu, 4); nr += __shfl_xor(nr, 4); nm += __shfl_xor(nm, 4);
            nu += __shfl_xor(nu, 8); nr += __shfl_xor(nr, 8); nm += __shfl_xor(nm, 8);
            if (r == 0) {
                float den = fmaxf(sqrtf(nr * nm), 1e-8f);
                out[(bn * TT + t) * 3 + e] = nu / den;
            }
        }
}

extern "C" void kernel_launch(void* const* d_in, const int* in_sizes, int n_in,
                              void* d_out, int out_size, void* d_ws, size_t ws_size,
                              hipStream_t stream) {
    const float* input       = (const float*)d_in[0];
    const float* h0          = (const float*)d_in[1];
    const float* h1          = (const float*)d_in[2];
    const float* h2          = (const float*)d_in[3];
    const float* memory      = (const float*)d_in[4];
    const float* input_query = (const float*)d_in[5];
    const float* hid_query   = (const float*)d_in[6];
    const float* key_w       = (const float*)d_in[7];
    const float* value_w     = (const float*)d_in[8];
    float* out = (float*)d_out;
    _Float16* ws = (_Float16*)d_ws;   // 40960 bytes used

    hipLaunchKernelGGL(prep_frags, dim3(80), dim3(256), 0, stream,
                       hid_query, key_w, value_w, memory, ws);
    hipLaunchKernelGGL(testam_wave, dim3(16 * 1024, 3), dim3(64), 0, stream,
                       input, h0, h1, h2, input_query, ws, out);
}

// Round 6
// 260.605 us; speedup vs baseline: 4.2852x; 1.1422x over previous
//
#include <hip/hip_runtime.h>

typedef _Float16 half8 __attribute__((ext_vector_type(8)));
typedef __fp16 fp16x2 __attribute__((ext_vector_type(2)));
typedef float floatx4 __attribute__((ext_vector_type(4)));
typedef unsigned int uint;
typedef uint uint4t __attribute__((ext_vector_type(4)));

namespace {
constexpr int TT = 48, HID = 64, MH = 32, MS = 20;
constexpr int VSTR = 72;    // halves per vT row (144 B, conflict-free b128)
constexpr int PMSTR = 40;   // halves per phase-A P row
constexpr int LDS_BYTES = 4608;   // vT [32][72] halves; phase-A pm aliases it
// d_ws offsets in half elements (total 32768 halves = 64 KiB)
constexpr int WS_WV   = 0;        // value_w B-frags: [e][kk][nb] * 512
constexpr int WS_MEMA = 6144;     // mem A-frags (rows s, zero s>=20): 1024
constexpr int WS_MEMB = 7168;     // mem B-frags (k=s, col m, zero s>=20): 1024
constexpr int WS_M    = 8192;     // M^T A-frags: [e][hl][tbG][ak] * 512 = 24576
}

static __device__ inline uint pk2(float a, float b) {
    fp16x2 h = __builtin_amdgcn_cvt_pkrtz(a, b);
    return __builtin_bit_cast(uint, h);
}
static __device__ inline half8 mk8(uint a, uint b, uint c, uint d) {
    uint4t u = {a, b, c, d};
    return __builtin_bit_cast(half8, u);
}

// Prep: per-expert M = Wq*Wk^T (fp32) -> M^T A-frags hi/lo; value_w B-frags; mem frags.
__global__ __launch_bounds__(256)
void prep_frags(const float* __restrict__ hid_query,
                const float* __restrict__ key_w,
                const float* __restrict__ value_w,
                const float* __restrict__ memory,
                _Float16* __restrict__ ws)
{
    const int e = blockIdx.x, tid = threadIdx.x;
    __shared__ float sWq[HID * MH], sWk[HID * MH], sM[HID * HID];
    for (int i = tid; i < HID * MH; i += 256) {
        sWq[i] = hid_query[e * HID * MH + i];
        sWk[i] = key_w[e * HID * MH + i];
    }
    __syncthreads();
    for (int i = tid; i < HID * HID; i += 256) {
        int a = i >> 6, b = i & 63;
        float acc = 0.f;
        #pragma unroll
        for (int m = 0; m < MH; ++m) acc = fmaf(sWq[a * MH + m], sWk[b * MH + m], acc);
        sM[i] = acc;
    }
    __syncthreads();
    // M^T A-frags: lane l elem j of frag [hl][tbG][ak] = M[32ak+8*(l>>4)+j][16tbG+(l&15)]
    for (int i = tid; i < 16 * 512; i += 256) {
        int j = i & 7, lane = (i >> 3) & 63, ak = (i >> 9) & 1, tbG = (i >> 10) & 3, hl = (i >> 12) & 1;
        float v = sM[(32 * ak + 8 * (lane >> 4) + j) * 64 + 16 * tbG + (lane & 15)];
        _Float16 hi = (_Float16)v;
        ws[WS_M + (size_t)((((e * 2 + hl) * 4 + tbG) * 2 + ak) << 9) + (i & 511)] =
            hl ? (_Float16)(v - (float)hi) : hi;
    }
    // value_w B-frags: frag [kk][nb]: W[kk*32+(l>>4)*8+j][nb*16+(l&15)]
    for (int i = tid; i < 2048; i += 256) {
        int j = i & 7, lane = (i >> 3) & 63, nb = (i >> 9) & 1, kk = (i >> 10) & 1;
        int h = kk * 32 + (lane >> 4) * 8 + j;
        int m = nb * 16 + (lane & 15);
        ws[WS_WV + e * 2048 + (i & 2047)] = (_Float16)value_w[((size_t)e * HID + h) * MH + m];
    }
    if (e == 0) {
        for (int i = tid; i < 1024; i += 256) {
            int j = i & 7, lane = (i >> 3) & 63, sb = i >> 9;
            int s = 16 * sb + (lane & 15);
            int m = (lane >> 4) * 8 + j;
            ws[WS_MEMA + i] = (s < MS) ? (_Float16)memory[s * MH + m] : (_Float16)0.f;
        }
        for (int i = tid; i < 1024; i += 256) {
            int j = i & 7, lane = (i >> 3) & 63, nb = i >> 9;
            int s = (lane >> 4) * 8 + j;
            int m = 16 * nb + (lane & 15);
            ws[WS_MEMB + i] = (s < MS) ? (_Float16)memory[s * MH + m] : (_Float16)0.f;
        }
    }
}

// One wave per (bn, expert); 4608 B LDS -> 16 waves/CU (VGPR-capped at 128).
__global__ __launch_bounds__(64, 4)
void testam_wave(const float* __restrict__ input,
                 const float* __restrict__ h0,
                 const float* __restrict__ h1,
                 const float* __restrict__ h2,
                 const float* __restrict__ input_query,
                 const _Float16* __restrict__ ws,
                 float* __restrict__ out)
{
    __shared__ __align__(16) char smem[LDS_BYTES];
    const int lane = threadIdx.x;
    const int r = lane & 15, g = lane >> 4;
    const size_t bn = blockIdx.x;
    const int e = blockIdx.y;

    _Float16* s_vt = (_Float16*)smem;   // [32][72] halves
    _Float16* s_pm = (_Float16*)smem;   // phase-A P [48][40] (aliases vT; vT dead by then)

    const float* hp = (e == 0) ? h0 : (e == 1 ? h1 : h2);
    const float* hb = hp + bn * (size_t)(TT * HID);

    // ---- h A-frags, hi/lo f16 split ----
    half8 Ahi[3][2], Alo[3][2];
    #pragma unroll
    for (int tb = 0; tb < 3; ++tb)
        #pragma unroll
        for (int kk = 0; kk < 2; ++kk) {
            const float* src = hb + (tb * 16 + r) * HID + kk * 32 + g * 8;
            float4 x0 = *(const float4*)src;
            float4 x1 = *(const float4*)(src + 4);
            float xs[8] = {x0.x, x0.y, x0.z, x0.w, x1.x, x1.y, x1.z, x1.w};
            half8 hi, lo;
            #pragma unroll
            for (int j = 0; j < 8; ++j) {
                _Float16 hh = (_Float16)xs[j];
                hi[j] = hh;
                lo[j] = (_Float16)(xs[j] - (float)hh);
            }
            Ahi[tb][kk] = hi; Alo[tb][kk] = lo;
        }

    // ---- v projection -> vT LDS (B-operand of PV) ----
    {
        half8 WV[2][2];
        #pragma unroll
        for (int kk = 0; kk < 2; ++kk)
            #pragma unroll
            for (int nb = 0; nb < 2; ++nb)
                WV[kk][nb] = *(const half8*)(ws + WS_WV + e * 2048 + (size_t)((kk * 2 + nb) * 64 + lane) * 8);
        floatx4 vacc[3][2];
        #pragma unroll
        for (int tb = 0; tb < 3; ++tb) { vacc[tb][0] = (floatx4)0.f; vacc[tb][1] = (floatx4)0.f; }
        #pragma unroll
        for (int kk = 0; kk < 2; ++kk)
            #pragma unroll
            for (int tb = 0; tb < 3; ++tb)
                #pragma unroll
                for (int nb = 0; nb < 2; ++nb) {
                    vacc[tb][nb] = __builtin_amdgcn_mfma_f32_16x16x32_f16(Alo[tb][kk], WV[kk][nb], vacc[tb][nb], 0, 0, 0);
                    vacc[tb][nb] = __builtin_amdgcn_mfma_f32_16x16x32_f16(Ahi[tb][kk], WV[kk][nb], vacc[tb][nb], 0, 0, 0);
                }
        #pragma unroll
        for (int tb = 0; tb < 3; ++tb)
            #pragma unroll
            for (int nb = 0; nb < 2; ++nb)
                #pragma unroll
                for (int rr = 0; rr < 4; ++rr)
                    s_vt[(nb * 16 + r) * VSTR + tb * 16 + g * 4 + rr] = (_Float16)vacc[tb][nb][rr];
        #pragma unroll
        for (int i = lane; i < 32 * 8; i += 64) {   // zero pad rows s=48..63
            int row = i >> 3, c = 48 + ((i & 7) << 1);
            *(uint*)&s_vt[row * VSTR + c] = 0u;
        }
    }
    asm volatile("" ::: "memory");

    // ---- E' = energy^T via G^T = M^T h^T (all in registers) ----
    const int laneA = (g & 1) * 32 + r;   // src lane for j<4 in the cheap regroup
    const bool hiT = (g >= 2);

    floatx4 E[3][3];
    #pragma unroll
    for (int tb = 0; tb < 3; ++tb)
        #pragma unroll
        for (int nb = 0; nb < 3; ++nb) E[tb][nb] = (floatx4)0.f;

    #pragma unroll
    for (int kk = 0; kk < 2; ++kk) {
        floatx4 Gacc[2][3];
        #pragma unroll
        for (int t = 0; t < 2; ++t)
            #pragma unroll
            for (int nb = 0; nb < 3; ++nb) Gacc[t][nb] = (floatx4)0.f;
        #pragma unroll
        for (int tbL = 0; tbL < 2; ++tbL) {
            const int tbG = kk * 2 + tbL;
            #pragma unroll
            for (int ak = 0; ak < 2; ++ak) {
                half8 Mhi = *(const half8*)(ws + WS_M + (size_t)(((((e * 2 + 0) * 4 + tbG) * 2 + ak) * 64 + lane)) * 8);
                half8 Mlo = *(const half8*)(ws + WS_M + (size_t)(((((e * 2 + 1) * 4 + tbG) * 2 + ak) * 64 + lane)) * 8);
                #pragma unroll
                for (int nb = 0; nb < 3; ++nb) {
                    Gacc[tbL][nb] = __builtin_amdgcn_mfma_f32_16x16x32_f16(Mlo, Ahi[nb][ak], Gacc[tbL][nb], 0, 0, 0);
                    Gacc[tbL][nb] = __builtin_amdgcn_mfma_f32_16x16x32_f16(Mhi, Alo[nb][ak], Gacc[tbL][nb], 0, 0, 0);
                    Gacc[tbL][nb] = __builtin_amdgcn_mfma_f32_16x16x32_f16(Mhi, Ahi[nb][ak], Gacc[tbL][nb], 0, 0, 0);
                }
            }
        }
        // regroup G^T C-layout -> B-frags (hi/lo): 2 shfl + 1 select per dword
        #pragma unroll
        for (int nb = 0; nb < 3; ++nb) {
            uint pkh[2][2], pkl[2][2];
            #pragma unroll
            for (int t = 0; t < 2; ++t)
                #pragma unroll
                for (int d = 0; d < 2; ++d) {
                    float x0 = Gacc[t][nb][2 * d], x1 = Gacc[t][nb][2 * d + 1];
                    fp16x2 h = __builtin_amdgcn_cvt_pkrtz(x0, x1);
                    pkh[t][d] = __builtin_bit_cast(uint, h);
                    pkl[t][d] = pk2(x0 - (float)h[0], x1 - (float)h[1]);
                }
            uint wh[4], wl[4];
            #pragma unroll
            for (int d = 0; d < 2; ++d) {
                int h0a = __shfl((int)pkh[0][d], laneA);
                int h1a = __shfl((int)pkh[1][d], laneA);
                int h0b = __shfl((int)pkh[0][d], laneA + 16);
                int h1b = __shfl((int)pkh[1][d], laneA + 16);
                wh[d]     = hiT ? (uint)h1a : (uint)h0a;
                wh[2 + d] = hiT ? (uint)h1b : (uint)h0b;
                int l0a = __shfl((int)pkl[0][d], laneA);
                int l1a = __shfl((int)pkl[1][d], laneA);
                int l0b = __shfl((int)pkl[0][d], laneA + 16);
                int l1b = __shfl((int)pkl[1][d], laneA + 16);
                wl[d]     = hiT ? (uint)l1a : (uint)l0a;
                wl[2 + d] = hiT ? (uint)l1b : (uint)l0b;
            }
            half8 Bhi = mk8(wh[0], wh[1], wh[2], wh[3]);
            half8 Blo = mk8(wl[0], wl[1], wl[2], wl[3]);
            #pragma unroll
            for (int tb = 0; tb < 3; ++tb) {
                E[tb][nb] = __builtin_amdgcn_mfma_f32_16x16x32_f16(Alo[tb][kk], Bhi, E[tb][nb], 0, 0, 0);
                E[tb][nb] = __builtin_amdgcn_mfma_f32_16x16x32_f16(Ahi[tb][kk], Blo, E[tb][nb], 0, 0, 0);
                E[tb][nb] = __builtin_amdgcn_mfma_f32_16x16x32_f16(Ahi[tb][kk], Bhi, E[tb][nb], 0, 0, 0);
            }
        }
    }

    // ---- softmax over s (rows of E') per t-col; numerators only ----
    #pragma unroll
    for (int nb = 0; nb < 3; ++nb) {
        float m = E[0][nb][0];
        #pragma unroll
        for (int tb = 0; tb < 3; ++tb)
            #pragma unroll
            for (int rr = 0; rr < 4; ++rr) m = fmaxf(m, E[tb][nb][rr]);
        m = fmaxf(m, __shfl_xor(m, 16));
        m = fmaxf(m, __shfl_xor(m, 32));
        #pragma unroll
        for (int tb = 0; tb < 3; ++tb)
            #pragma unroll
            for (int rr = 0; rr < 4; ++rr) E[tb][nb][rr] = __expf(E[tb][nb][rr] - m);
    }

    // ---- P'^T A-frags via the same cheap regroup (no LDS) ----
    half8 PF[3][2];
    #pragma unroll
    for (int tbT = 0; tbT < 3; ++tbT) {
        uint pk[3][2];
        #pragma unroll
        for (int t = 0; t < 3; ++t)
            #pragma unroll
            for (int d = 0; d < 2; ++d)
                pk[t][d] = pk2(E[t][tbT][2 * d], E[t][tbT][2 * d + 1]);
        uint w0[4], w1[4];
        #pragma unroll
        for (int d = 0; d < 2; ++d) {
            int a0 = __shfl((int)pk[0][d], laneA);
            int a1 = __shfl((int)pk[1][d], laneA);
            int b0 = __shfl((int)pk[0][d], laneA + 16);
            int b1 = __shfl((int)pk[1][d], laneA + 16);
            w0[d]     = hiT ? (uint)a1 : (uint)a0;
            w0[2 + d] = hiT ? (uint)b1 : (uint)b0;
            int a2 = __shfl((int)pk[2][d], laneA);
            int b2 = __shfl((int)pk[2][d], laneA + 16);
            w1[d]     = hiT ? 0u : (uint)a2;     // rows s>=48 are zero pad
            w1[2 + d] = hiT ? 0u : (uint)b2;
        }
        PF[tbT][0] = mk8(w0[0], w0[1], w0[2], w0[3]);
        PF[tbT][1] = mk8(w1[0], w1[1], w1[2], w1[3]);
    }

    // ---- att = P'^T @ v ----
    floatx4 att[3][2];
    #pragma unroll
    for (int tb = 0; tb < 3; ++tb) { att[tb][0] = (floatx4)0.f; att[tb][1] = (floatx4)0.f; }
    #pragma unroll
    for (int kk = 0; kk < 2; ++kk) {
        half8 vb0 = *(const half8*)&s_vt[(0 * 16 + r) * VSTR + kk * 32 + g * 8];
        half8 vb1 = *(const half8*)&s_vt[(1 * 16 + r) * VSTR + kk * 32 + g * 8];
        #pragma unroll
        for (int tb = 0; tb < 3; ++tb) {
            att[tb][0] = __builtin_amdgcn_mfma_f32_16x16x32_f16(PF[tb][kk], vb0, att[tb][0], 0, 0, 0);
            att[tb][1] = __builtin_amdgcn_mfma_f32_16x16x32_f16(PF[tb][kk], vb1, att[tb][1], 0, 0, 0);
        }
    }
    asm volatile("" ::: "memory");   // vT dead; s_pm may now overwrite it

    // ---- phase A (moved to end): memory read-out, all-MFMA ----
    half8 memA0 = *(const half8*)(ws + WS_MEMA + (size_t)lane * 8);
    half8 memA1 = *(const half8*)(ws + WS_MEMA + (size_t)(64 + lane) * 8);
    half8 memB0 = *(const half8*)(ws + WS_MEMB + (size_t)lane * 8);
    half8 memB1 = *(const half8*)(ws + WS_MEMB + (size_t)(64 + lane) * 8);

    float4 iqa = *(const float4*)(input_query + g * 8);
    float4 iqb = *(const float4*)(input_query + g * 8 + 4);
    float4 iqc = *(const float4*)(input_query + 32 + g * 8);
    float4 iqd = *(const float4*)(input_query + 32 + g * 8 + 4);
    float iq0[8] = {iqa.x, iqa.y, iqa.z, iqa.w, iqb.x, iqb.y, iqb.z, iqb.w};
    float iq1[8] = {iqc.x, iqc.y, iqc.z, iqc.w, iqd.x, iqd.y, iqd.z, iqd.w};

    floatx4 Em[2][3];
    #pragma unroll
    for (int tb = 0; tb < 3; ++tb) {
        const float2 in2 = *(const float2*)(input + bn * 96 + (16 * tb + r) * 2);
        half8 qb;
        #pragma unroll
        for (int j = 0; j < 8; ++j)
            qb[j] = (_Float16)(in2.x * iq0[j] + in2.y * iq1[j]);
        Em[0][tb] = __builtin_amdgcn_mfma_f32_16x16x32_f16(memA0, qb, (floatx4)0.f, 0, 0, 0);
        Em[1][tb] = __builtin_amdgcn_mfma_f32_16x16x32_f16(memA1, qb, (floatx4)0.f, 0, 0, 0);
    }
    #pragma unroll
    for (int tb = 0; tb < 3; ++tb) {
        float mx = Em[0][tb][0];
        #pragma unroll
        for (int rr = 1; rr < 4; ++rr) mx = fmaxf(mx, Em[0][tb][rr]);
        #pragma unroll
        for (int rr = 0; rr < 4; ++rr) mx = fmaxf(mx, Em[1][tb][rr]);
        mx = fmaxf(mx, __shfl_xor(mx, 16));
        mx = fmaxf(mx, __shfl_xor(mx, 32));
        #pragma unroll
        for (int sb = 0; sb < 2; ++sb)
            #pragma unroll
            for (int rr = 0; rr < 4; ++rr)
                s_pm[(16 * tb + r) * PMSTR + 16 * sb + 4 * g + rr] =
                    (_Float16)__expf(Em[sb][tb][rr] - mx);
    }
    asm volatile("" ::: "memory");
    floatx4 mems[3][2];
    #pragma unroll
    for (int tb = 0; tb < 3; ++tb) {
        half8 pA = *(const half8*)&s_pm[(16 * tb + r) * PMSTR + g * 8];
        mems[tb][0] = __builtin_amdgcn_mfma_f32_16x16x32_f16(pA, memB0, (floatx4)0.f, 0, 0, 0);
        mems[tb][1] = __builtin_amdgcn_mfma_f32_16x16x32_f16(pA, memB1, (floatx4)0.f, 0, 0, 0);
    }

    // ---- cosine(att, memories); reduce over m via 16-lane xor ----
    #pragma unroll
    for (int tb = 0; tb < 3; ++tb)
        #pragma unroll
        for (int rr = 0; rr < 4; ++rr) {
            int t = 16 * tb + 4 * g + rr;
            float a0 = att[tb][0][rr], a1 = att[tb][1][rr];
            float m0 = mems[tb][0][rr], m1 = mems[tb][1][rr];
            float nu = a0 * m0 + a1 * m1;
            float nr = a0 * a0 + a1 * a1;
            float nm = m0 * m0 + m1 * m1;
            nu += __shfl_xor(nu, 1); nr += __shfl_xor(nr, 1); nm += __shfl_xor(nm, 1);
            nu += __shfl_xor(nu, 2); nr += __shfl_xor(nr, 2); nm += __shfl_xor(nm, 2);
            nu += __shfl_xor(nu, 4); nr += __shfl_xor(nr, 4); nm += __shfl_xor(nm, 4);
            nu += __shfl_xor(nu, 8); nr += __shfl_xor(nr, 8); nm += __shfl_xor(nm, 8);
            if (r == 0) {
                float den = fmaxf(sqrtf(nr * nm), 1e-8f);
                out[(bn * TT + t) * 3 + e] = nu / den;
            }
        }
}

extern "C" void kernel_launch(void* const* d_in, const int* in_sizes, int n_in,
                              void* d_out, int out_size, void* d_ws, size_t ws_size,
                              hipStream_t stream) {
    const float* input       = (const float*)d_in[0];
    const float* h0          = (const float*)d_in[1];
    const float* h1          = (const float*)d_in[2];
    const float* h2          = (const float*)d_in[3];
    const float* memory      = (const float*)d_in[4];
    const float* input_query = (const float*)d_in[5];
    const float* hid_query   = (const float*)d_in[6];
    const float* key_w       = (const float*)d_in[7];
    const float* value_w     = (const float*)d_in[8];
    float* out = (float*)d_out;
    _Float16* ws = (_Float16*)d_ws;   // 65536 bytes used

    hipLaunchKernelGGL(prep_frags, dim3(3), dim3(256), 0, stream,
                       hid_query, key_w, value_w, memory, ws);
    hipLaunchKernelGGL(testam_wave, dim3(16 * 1024, 3), dim3(64), 0, stream,
                       input, h0, h1, h2, input_query, ws, out);
}